// Round 3
// baseline (178.571 us; speedup 1.0000x reference)
//
#include <hip/hip_runtime.h>

#define IN_DIM 128
#define OUT_DIM 128

typedef __attribute__((ext_vector_type(8))) short short8v;   // 8 bf16 = 4 VGPRs
typedef __attribute__((ext_vector_type(4))) float float4v;
typedef __attribute__((ext_vector_type(4))) unsigned int uint4v;

__device__ __forceinline__ ushort f2bf(float f) {
    unsigned int u = __builtin_bit_cast(unsigned int, f);
    unsigned int r = (u + 0x7fffu + ((u >> 16) & 1u)) >> 16;   // RNE
    return (ushort)r;
}

__device__ __forceinline__ unsigned int pk2bf(float x, float y) {
#if __has_builtin(__builtin_amdgcn_cvt_pk_bf16_f32)
    typedef __attribute__((ext_vector_type(2))) __bf16 bf2;
    bf2 r = __builtin_amdgcn_cvt_pk_bf16_f32(x, y);
    return __builtin_bit_cast(unsigned int, r);
#else
    return (unsigned int)f2bf(x) | ((unsigned int)f2bf(y) << 16);
#endif
}

// ---------------- Kernel 0: prep (Wt only, 16 blocks) ----------------
// Wt[n][k] = bf16(W[k][n]), row stride 136. Coalesced fp32 reads, b32 stores.
__global__ __launch_bounds__(256) void prep_kernel(const float* __restrict__ W,
                                                   ushort* __restrict__ Wt) {
    int k0 = blockIdx.x * 8;
    int n = threadIdx.x & 127;
    int half = threadIdx.x >> 7;
#pragma unroll
    for (int kp = 0; kp < 2; ++kp) {
        int k = k0 + (half * 2 + kp) * 2;
        float v0 = W[k * 128 + n];          // coalesced across lanes
        float v1 = W[(k + 1) * 128 + n];
        *(unsigned int*)&Wt[n * 136 + k] = pk2bf(v0, v1);
    }
}

// ---------------- Kernel 1: T(biased-uint8, per-row scale) = H @ W, + rp tail ----------------
// Blocks [0, nb_gemm): 64-row x 128-col tile, K=128 unrolled (proven core).
// Epilogue: per-row absmax (shfl_xor 16/32 over quarter-lanes), quantize row
// to BIASED uint8 (q+128) with scale S[row] = rowmax/127 -> fetch-cheap
// scatter gather AND single-instruction v_cvt_f32_ubyte decode.
// Blocks [nb_gemm, ...): row_ptr[n] = lower_bound(edst, n) (overlaps gemm).
__global__ __launch_bounds__(256) void gemm_kernel(const float* __restrict__ H,
                                                   const ushort* __restrict__ Wt_g,
                                                   unsigned char* __restrict__ T8,
                                                   float* __restrict__ S, int M,
                                                   const int* __restrict__ edst,
                                                   int* __restrict__ rp,
                                                   int E, int nb_gemm) {
    __shared__ ushort Ws[128 * 136];   // 34816 B

    const int t = threadIdx.x;

    if (blockIdx.x >= nb_gemm) {       // rp tail blocks (block-uniform branch)
        int n = (blockIdx.x - nb_gemm) * 256 + t;
        if (n <= M) {
            int lo = 0, hi = E;
            while (lo < hi) {
                int mid = (lo + hi) >> 1;
                if (edst[mid] < n) lo = mid + 1; else hi = mid;
            }
            rp[n] = lo;
        }
        return;
    }

    const int row0 = blockIdx.x * 64;

#pragma unroll
    for (int f = t; f < 2176; f += 256)
        ((short8v*)Ws)[f] = ((const short8v*)Wt_g)[f];

    const int w = t >> 6;
    const int l = t & 63;
    const int m16 = l & 15;
    const int kq = (l >> 4) * 8;
    const int gr = row0 + w * 16 + m16;

    float4 h[8];
    if (gr < M) {
#pragma unroll
        for (int ks = 0; ks < 4; ++ks) {
            h[ks * 2]     = *(const float4*)&H[gr * 128 + ks * 32 + kq];
            h[ks * 2 + 1] = *(const float4*)&H[gr * 128 + ks * 32 + kq + 4];
        }
    } else {
#pragma unroll
        for (int i = 0; i < 8; ++i) h[i] = make_float4(0.f, 0.f, 0.f, 0.f);
    }

    short8v bfrag[4];
#pragma unroll
    for (int ks = 0; ks < 4; ++ks) {
        uint4v u;
        u[0] = pk2bf(h[ks * 2].x, h[ks * 2].y);
        u[1] = pk2bf(h[ks * 2].z, h[ks * 2].w);
        u[2] = pk2bf(h[ks * 2 + 1].x, h[ks * 2 + 1].y);
        u[3] = pk2bf(h[ks * 2 + 1].z, h[ks * 2 + 1].w);
        bfrag[ks] = __builtin_bit_cast(short8v, u);
    }

    __syncthreads();   // Ws ready

    float4v acc[8];
#pragma unroll
    for (int nt = 0; nt < 8; ++nt) acc[nt] = (float4v){0.f, 0.f, 0.f, 0.f};

#pragma unroll
    for (int ks = 0; ks < 4; ++ks) {
#pragma unroll
        for (int nt = 0; nt < 8; ++nt) {
            short8v afrag = *(const short8v*)&Ws[(nt * 16 + m16) * 136 + ks * 32 + kq];
            acc[nt] = __builtin_amdgcn_mfma_f32_16x16x32_bf16(afrag, bfrag[ks], acc[nt], 0, 0, 0);
        }
    }

    // Per-row absmax across this lane's 32 cols, then across the 4 quarter-
    // lanes sharing row gr (l, l^16, l^32, l^48).
    float mx = 0.f;
#pragma unroll
    for (int nt = 0; nt < 8; ++nt) {
#pragma unroll
        for (int k = 0; k < 4; ++k) mx = fmaxf(mx, fabsf(acc[nt][k]));
    }
    mx = fmaxf(mx, __shfl_xor(mx, 16));
    mx = fmaxf(mx, __shfl_xor(mx, 32));

    const float inv = 127.0f / fmaxf(mx, 1e-20f);

    if (gr < M) {
        const int qd = l >> 4;
        if (qd == 0) S[gr] = mx * (1.0f / 127.0f);
#pragma unroll
        for (int nt = 0; nt < 8; ++nt) {
            unsigned int p = 0;
#pragma unroll
            for (int k = 0; k < 4; ++k) {
                int qi = (int)__builtin_rintf(acc[nt][k] * inv);
                qi = qi > 127 ? 127 : (qi < -127 ? -127 : qi);
                p |= ((unsigned int)(qi + 128) & 0xffu) << (k * 8);   // biased
            }
            *(unsigned int*)&T8[gr * 128 + nt * 16 + qd * 4] = p;
        }
    }
}

// ---------------- Kernel 2: out[n][:] = b + sum_{e} w_e*S[src]*(T8[src][:]-128) ----------------
// One wave per node; lane owns 2 cols (one ushort = 2 biased-uint8 of the row
// -> 128 B/edge gather, half of f16). Edge metadata via wave-uniform (scalar-
// pipe) loads: rp[] through readfirstlane makes the loop counter provably
// uniform -> s_load per batch; S[src] also uniform -> scalar load.
// Per edge: 1 gather ushort + v_mul(ws) + v_add(B) + 2x v_cvt_f32_ubyte +
// 2x v_fmac = 6 VALU ops. Bias correction -128*B applied once at the end.
__global__ __launch_bounds__(256) void scatter_kernel(const ushort* __restrict__ T16,
                                                      const float* __restrict__ S,
                                                      const int* __restrict__ esrc,
                                                      const float* __restrict__ ew,
                                                      const int* __restrict__ rp,
                                                      const float* __restrict__ b,
                                                      float* __restrict__ out) {
    const int node = blockIdx.x * 4 + (threadIdx.x >> 6);
    const int lane = threadIdx.x & 63;

    const int s = __builtin_amdgcn_readfirstlane(rp[node]);
    const int e = __builtin_amdgcn_readfirstlane(rp[node + 1]);

    float ax = 0.f, ay = 0.f;   // unbiased accumulators
    float B = 0.f;              // sum of ws for bias correction

    int c = s;
    for (; c + 8 <= e; c += 8) {
#pragma unroll
        for (int q = 0; q < 8; ++q) {
            const int   sq = esrc[c + q];             // uniform -> s_load
            const float wq = ew[c + q];               // uniform -> s_load
            const float ws = wq * S[sq];              // uniform scalar load + v_mul
            B += ws;
            unsigned int v = T16[(unsigned int)sq * 64u + (unsigned int)lane];
            ax = fmaf((float)(v & 0xffu), ws, ax);          // v_cvt_f32_ubyte0 + fmac
            ay = fmaf((float)((v >> 8) & 0xffu), ws, ay);   // v_cvt_f32_ubyte1 + fmac
        }
    }
    for (; c < e; ++c) {
        const int   sq = esrc[c];
        const float wq = ew[c];
        const float ws = wq * S[sq];
        B += ws;
        unsigned int v = T16[(unsigned int)sq * 64u + (unsigned int)lane];
        ax = fmaf((float)(v & 0xffu), ws, ax);
        ay = fmaf((float)((v >> 8) & 0xffu), ws, ay);
    }

    float2 bias = *(const float2*)&b[lane * 2];
    float ox = fmaf(-128.0f, B, ax) + bias.x;
    float oy = fmaf(-128.0f, B, ay) + bias.y;

    *(float2*)&out[node * 128 + lane * 2] = make_float2(ox, oy);
}

extern "C" void kernel_launch(void* const* d_in, const int* in_sizes, int n_in,
                              void* d_out, int out_size, void* d_ws, size_t ws_size,
                              hipStream_t stream) {
    const float* H    = (const float*)d_in[0];
    const int*   esrc = (const int*)d_in[1];
    const int*   edst = (const int*)d_in[2];
    const float* ew   = (const float*)d_in[3];
    const float* W    = (const float*)d_in[4];
    const float* b    = (const float*)d_in[5];
    float* out = (float*)d_out;

    const int M = in_sizes[0] / IN_DIM;   // 50000 nodes
    const int E = in_sizes[1];            // 1,600,000 edges

    // Workspace layout
    unsigned char* T8 = (unsigned char*)d_ws;                       // M*128 bytes (biased uint8)
    size_t off = (size_t)M * 128;
    float* S  = (float*)((char*)d_ws + off);                        // M floats
    off += (size_t)M * 4;
    ushort* Wt = (ushort*)((char*)d_ws + off);                      // 128*136*2 B
    off += 128 * 136 * 2;
    int* rp = (int*)((char*)d_ws + off);                            // (M+1) ints

    // Wt transpose (16 blocks)
    prep_kernel<<<16, 256, 0, stream>>>(W, Wt);

    // gemm (biased-uint8 output + per-row scale) + rp tail blocks
    const int nb_gemm = (M + 63) / 64;         // 782
    const int nb_rp   = (M + 1 + 255) / 256;   // 196
    gemm_kernel<<<nb_gemm + nb_rp, 256, 0, stream>>>(H, Wt, T8, S, M, edst, rp, E, nb_gemm);

    scatter_kernel<<<(M + 3) / 4, 256, 0, stream>>>((const ushort*)T8, S, esrc, ew, rp, b, out);
}

// Round 4
// 147.827 us; speedup vs baseline: 1.2080x; 1.2080x over previous
//
#include <hip/hip_runtime.h>

#define IN_DIM 128
#define OUT_DIM 128

typedef __attribute__((ext_vector_type(8))) short short8v;   // 8 bf16 = 4 VGPRs
typedef __attribute__((ext_vector_type(4))) float float4v;
typedef __attribute__((ext_vector_type(4))) unsigned int uint4v;
typedef __attribute__((ext_vector_type(4))) int int4v;

__device__ __forceinline__ ushort f2bf(float f) {
    unsigned int u = __builtin_bit_cast(unsigned int, f);
    unsigned int r = (u + 0x7fffu + ((u >> 16) & 1u)) >> 16;   // RNE
    return (ushort)r;
}

__device__ __forceinline__ unsigned int pk2bf(float x, float y) {
#if __has_builtin(__builtin_amdgcn_cvt_pk_bf16_f32)
    typedef __attribute__((ext_vector_type(2))) __bf16 bf2;
    bf2 r = __builtin_amdgcn_cvt_pk_bf16_f32(x, y);
    return __builtin_bit_cast(unsigned int, r);
#else
    return (unsigned int)f2bf(x) | ((unsigned int)f2bf(y) << 16);
#endif
}

// ---------------- Kernel 0: prep (Wt only, 16 blocks) ----------------
// Wt[n][k] = bf16(W[k][n]), row stride 136. Coalesced fp32 reads, b32 stores.
__global__ __launch_bounds__(256) void prep_kernel(const float* __restrict__ W,
                                                   ushort* __restrict__ Wt) {
    int k0 = blockIdx.x * 8;
    int n = threadIdx.x & 127;
    int half = threadIdx.x >> 7;
#pragma unroll
    for (int kp = 0; kp < 2; ++kp) {
        int k = k0 + (half * 2 + kp) * 2;
        float v0 = W[k * 128 + n];          // coalesced across lanes
        float v1 = W[(k + 1) * 128 + n];
        *(unsigned int*)&Wt[n * 136 + k] = pk2bf(v0, v1);
    }
}

// ---------------- Kernel 1: T(biased-uint8, per-row scale) = H @ W, + rp tail ----------------
// Blocks [0, nb_gemm): 64-row x 128-col tile, K=128 unrolled (proven core).
// Epilogue: per-row absmax (shfl_xor 16/32 over quarter-lanes), quantize row
// to BIASED uint8 (q+128) with scale S[row] = rowmax/127 -> fetch-cheap
// scatter gather AND single-instruction v_cvt_f32_ubyte decode.
// Blocks [nb_gemm, ...): row_ptr[n] = lower_bound(edst, n) (overlaps gemm).
__global__ __launch_bounds__(256) void gemm_kernel(const float* __restrict__ H,
                                                   const ushort* __restrict__ Wt_g,
                                                   unsigned char* __restrict__ T8,
                                                   float* __restrict__ S, int M,
                                                   const int* __restrict__ edst,
                                                   int* __restrict__ rp,
                                                   int E, int nb_gemm) {
    __shared__ ushort Ws[128 * 136];   // 34816 B

    const int t = threadIdx.x;

    if (blockIdx.x >= nb_gemm) {       // rp tail blocks (block-uniform branch)
        int n = (blockIdx.x - nb_gemm) * 256 + t;
        if (n <= M) {
            int lo = 0, hi = E;
            while (lo < hi) {
                int mid = (lo + hi) >> 1;
                if (edst[mid] < n) lo = mid + 1; else hi = mid;
            }
            rp[n] = lo;
        }
        return;
    }

    const int row0 = blockIdx.x * 64;

#pragma unroll
    for (int f = t; f < 2176; f += 256)
        ((short8v*)Ws)[f] = ((const short8v*)Wt_g)[f];

    const int w = t >> 6;
    const int l = t & 63;
    const int m16 = l & 15;
    const int kq = (l >> 4) * 8;
    const int gr = row0 + w * 16 + m16;

    float4 h[8];
    if (gr < M) {
#pragma unroll
        for (int ks = 0; ks < 4; ++ks) {
            h[ks * 2]     = *(const float4*)&H[gr * 128 + ks * 32 + kq];
            h[ks * 2 + 1] = *(const float4*)&H[gr * 128 + ks * 32 + kq + 4];
        }
    } else {
#pragma unroll
        for (int i = 0; i < 8; ++i) h[i] = make_float4(0.f, 0.f, 0.f, 0.f);
    }

    short8v bfrag[4];
#pragma unroll
    for (int ks = 0; ks < 4; ++ks) {
        uint4v u;
        u[0] = pk2bf(h[ks * 2].x, h[ks * 2].y);
        u[1] = pk2bf(h[ks * 2].z, h[ks * 2].w);
        u[2] = pk2bf(h[ks * 2 + 1].x, h[ks * 2 + 1].y);
        u[3] = pk2bf(h[ks * 2 + 1].z, h[ks * 2 + 1].w);
        bfrag[ks] = __builtin_bit_cast(short8v, u);
    }

    __syncthreads();   // Ws ready

    float4v acc[8];
#pragma unroll
    for (int nt = 0; nt < 8; ++nt) acc[nt] = (float4v){0.f, 0.f, 0.f, 0.f};

#pragma unroll
    for (int ks = 0; ks < 4; ++ks) {
#pragma unroll
        for (int nt = 0; nt < 8; ++nt) {
            short8v afrag = *(const short8v*)&Ws[(nt * 16 + m16) * 136 + ks * 32 + kq];
            acc[nt] = __builtin_amdgcn_mfma_f32_16x16x32_bf16(afrag, bfrag[ks], acc[nt], 0, 0, 0);
        }
    }

    // Per-row absmax across this lane's 32 cols, then across the 4 quarter-
    // lanes sharing row gr (l, l^16, l^32, l^48).
    float mx = 0.f;
#pragma unroll
    for (int nt = 0; nt < 8; ++nt) {
#pragma unroll
        for (int k = 0; k < 4; ++k) mx = fmaxf(mx, fabsf(acc[nt][k]));
    }
    mx = fmaxf(mx, __shfl_xor(mx, 16));
    mx = fmaxf(mx, __shfl_xor(mx, 32));

    const float inv = 127.0f / fmaxf(mx, 1e-20f);

    if (gr < M) {
        const int qd = l >> 4;
        if (qd == 0) S[gr] = mx * (1.0f / 127.0f);
#pragma unroll
        for (int nt = 0; nt < 8; ++nt) {
            unsigned int p = 0;
#pragma unroll
            for (int k = 0; k < 4; ++k) {
                int qi = (int)__builtin_rintf(acc[nt][k] * inv);
                qi = qi > 127 ? 127 : (qi < -127 ? -127 : qi);
                p |= ((unsigned int)(qi + 128) & 0xffu) << (k * 8);   // biased
            }
            *(unsigned int*)&T8[gr * 128 + nt * 16 + qd * 4] = p;
        }
    }
}

// ---------------- Kernel 1.5: ews[e] = ew[e] * S[esrc[e]] ----------------
// Edge-parallel: the S gather runs on the VECTOR pipe (64 independent
// gathers/wave in flight) instead of scatter's serial scalar-pipe loads.
// S is 200 KB -> L2-resident. ~19 MB of traffic total.
__global__ __launch_bounds__(256) void ews_kernel(const int* __restrict__ esrc,
                                                  const float* __restrict__ ew,
                                                  const float* __restrict__ S,
                                                  float* __restrict__ ews, int E) {
    const int tid = blockIdx.x * 256 + threadIdx.x;
    const int stride = gridDim.x * 256;
    const int n4 = E >> 2;
    for (int j = tid; j < n4; j += stride) {
        int4v s4 = ((const int4v*)esrc)[j];
        float4 w4 = ((const float4*)ew)[j];
        float4 r;
        r.x = w4.x * S[s4.x];
        r.y = w4.y * S[s4.y];
        r.z = w4.z * S[s4.z];
        r.w = w4.w * S[s4.w];
        ((float4*)ews)[j] = r;
    }
    for (int j = (n4 << 2) + tid; j < E; j += stride)
        ews[j] = ew[j] * S[esrc[j]];
}

// ---------------- Kernel 2: out[n][:] = b + sum_{e} ews_e*(T8[src][:]-128) ----------------
// One wave per node; lane owns 2 cols (one ushort = 2 biased-uint8 of the row
// -> 128 B/edge gather). Edge metadata via wave-uniform CONTIGUOUS scalar
// loads only (esrc, ews -> s_load_dwordx8 batches, addresses known ahead ->
// prefetchable). NO data-dependent scalar load (that chain was R3's 85 us).
// Per edge: 1 gather ushort + v_add(B) + 2x v_cvt_f32_ubyte + 2x v_fmac
// = 5 VALU ops. Bias correction -128*B applied once at the end.
__global__ __launch_bounds__(256) void scatter_kernel(const ushort* __restrict__ T16,
                                                      const int* __restrict__ esrc,
                                                      const float* __restrict__ ews,
                                                      const int* __restrict__ rp,
                                                      const float* __restrict__ b,
                                                      float* __restrict__ out) {
    const int node = blockIdx.x * 4 + (threadIdx.x >> 6);
    const int lane = threadIdx.x & 63;

    const int s = __builtin_amdgcn_readfirstlane(rp[node]);
    const int e = __builtin_amdgcn_readfirstlane(rp[node + 1]);

    float ax = 0.f, ay = 0.f;   // unbiased accumulators
    float B = 0.f;              // sum of ws for bias correction

    int c = s;
    for (; c + 8 <= e; c += 8) {
#pragma unroll
        for (int q = 0; q < 8; ++q) {
            const int   sq = esrc[c + q];             // uniform contiguous -> s_load
            const float ws = ews[c + q];              // uniform contiguous -> s_load
            B += ws;
            unsigned int v = T16[(unsigned int)sq * 64u + (unsigned int)lane];
            ax = fmaf((float)(v & 0xffu), ws, ax);          // v_cvt_f32_ubyte0 + fmac
            ay = fmaf((float)((v >> 8) & 0xffu), ws, ay);   // v_cvt_f32_ubyte1 + fmac
        }
    }
    for (; c < e; ++c) {
        const int   sq = esrc[c];
        const float ws = ews[c];
        B += ws;
        unsigned int v = T16[(unsigned int)sq * 64u + (unsigned int)lane];
        ax = fmaf((float)(v & 0xffu), ws, ax);
        ay = fmaf((float)((v >> 8) & 0xffu), ws, ay);
    }

    float2 bias = *(const float2*)&b[lane * 2];
    float ox = fmaf(-128.0f, B, ax) + bias.x;
    float oy = fmaf(-128.0f, B, ay) + bias.y;

    *(float2*)&out[node * 128 + lane * 2] = make_float2(ox, oy);
}

extern "C" void kernel_launch(void* const* d_in, const int* in_sizes, int n_in,
                              void* d_out, int out_size, void* d_ws, size_t ws_size,
                              hipStream_t stream) {
    const float* H    = (const float*)d_in[0];
    const int*   esrc = (const int*)d_in[1];
    const int*   edst = (const int*)d_in[2];
    const float* ew   = (const float*)d_in[3];
    const float* W    = (const float*)d_in[4];
    const float* b    = (const float*)d_in[5];
    float* out = (float*)d_out;

    const int M = in_sizes[0] / IN_DIM;   // 50000 nodes
    const int E = in_sizes[1];            // 1,600,000 edges

    // Workspace layout (~13.24 MB)
    unsigned char* T8 = (unsigned char*)d_ws;                       // M*128 B (biased uint8)
    size_t off = (size_t)M * 128;
    float* S  = (float*)((char*)d_ws + off);                        // M floats
    off += (size_t)M * 4;
    ushort* Wt = (ushort*)((char*)d_ws + off);                      // 128*136*2 B
    off += 128 * 136 * 2;
    int* rp = (int*)((char*)d_ws + off);                            // (M+1) ints
    off += (size_t)(M + 1) * 4;
    float* ews = (float*)((char*)d_ws + off);                       // E floats

    // Wt transpose (16 blocks)
    prep_kernel<<<16, 256, 0, stream>>>(W, Wt);

    // gemm (biased-uint8 output + per-row scale) + rp tail blocks
    const int nb_gemm = (M + 63) / 64;         // 782
    const int nb_rp   = (M + 1 + 255) / 256;   // 196
    gemm_kernel<<<nb_gemm + nb_rp, 256, 0, stream>>>(H, Wt, T8, S, M, edst, rp, E, nb_gemm);

    // ews = ew * S[esrc]  (vector-pipe gather of S)
    int nb_ews = ((E >> 2) + 255) / 256;
    if (nb_ews > 2048) nb_ews = 2048;
    if (nb_ews < 1) nb_ews = 1;
    ews_kernel<<<nb_ews, 256, 0, stream>>>(esrc, ew, S, ews, E);

    scatter_kernel<<<(M + 3) / 4, 256, 0, stream>>>((const ushort*)T8, esrc, ews, rp, b, out);
}

// Round 5
// 139.313 us; speedup vs baseline: 1.2818x; 1.0611x over previous
//
#include <hip/hip_runtime.h>

#define IN_DIM 128
#define OUT_DIM 128

typedef __attribute__((ext_vector_type(8))) short short8v;   // 8 bf16 = 4 VGPRs
typedef __attribute__((ext_vector_type(4))) float float4v;
typedef __attribute__((ext_vector_type(4))) unsigned int uint4v;

__device__ __forceinline__ ushort f2bf(float f) {
    unsigned int u = __builtin_bit_cast(unsigned int, f);
    unsigned int r = (u + 0x7fffu + ((u >> 16) & 1u)) >> 16;   // RNE
    return (ushort)r;
}

__device__ __forceinline__ unsigned int pk2bf(float x, float y) {
#if __has_builtin(__builtin_amdgcn_cvt_pk_bf16_f32)
    typedef __attribute__((ext_vector_type(2))) __bf16 bf2;
    bf2 r = __builtin_amdgcn_cvt_pk_bf16_f32(x, y);
    return __builtin_bit_cast(unsigned int, r);
#else
    return (unsigned int)f2bf(x) | ((unsigned int)f2bf(y) << 16);
#endif
}

// ---------------- Kernel 0: prep (Wt only, 16 blocks) ----------------
// Wt[n][k] = bf16(W[k][n]), row stride 136. Coalesced fp32 reads, b32 stores.
__global__ __launch_bounds__(256) void prep_kernel(const float* __restrict__ W,
                                                   ushort* __restrict__ Wt) {
    int k0 = blockIdx.x * 8;
    int n = threadIdx.x & 127;
    int half = threadIdx.x >> 7;
#pragma unroll
    for (int kp = 0; kp < 2; ++kp) {
        int k = k0 + (half * 2 + kp) * 2;
        float v0 = W[k * 128 + n];          // coalesced across lanes
        float v1 = W[(k + 1) * 128 + n];
        *(unsigned int*)&Wt[n * 136 + k] = pk2bf(v0, v1);
    }
}

// ---------------- Kernel 1: T(biased-uint8, per-row scale) = H @ W, + rp tail ----------------
// Blocks [0, nb_gemm): 64-row x 128-col tile, K=128 unrolled (proven core).
// Epilogue: per-row absmax (shfl_xor 16/32 over quarter-lanes), quantize row
// to BIASED uint8 (q+128) with scale S[row] = rowmax/127 -> fetch-cheap
// scatter gather AND single-instruction v_cvt_f32_ubyte decode.
// Blocks [nb_gemm, ...): row_ptr[n] = lower_bound(edst, n) (overlaps gemm).
__global__ __launch_bounds__(256) void gemm_kernel(const float* __restrict__ H,
                                                   const ushort* __restrict__ Wt_g,
                                                   unsigned char* __restrict__ T8,
                                                   float* __restrict__ S, int M,
                                                   const int* __restrict__ edst,
                                                   int* __restrict__ rp,
                                                   int E, int nb_gemm) {
    __shared__ ushort Ws[128 * 136];   // 34816 B

    const int t = threadIdx.x;

    if (blockIdx.x >= nb_gemm) {       // rp tail blocks (block-uniform branch)
        int n = (blockIdx.x - nb_gemm) * 256 + t;
        if (n <= M) {
            int lo = 0, hi = E;
            while (lo < hi) {
                int mid = (lo + hi) >> 1;
                if (edst[mid] < n) lo = mid + 1; else hi = mid;
            }
            rp[n] = lo;
        }
        return;
    }

    const int row0 = blockIdx.x * 64;

#pragma unroll
    for (int f = t; f < 2176; f += 256)
        ((short8v*)Ws)[f] = ((const short8v*)Wt_g)[f];

    const int w = t >> 6;
    const int l = t & 63;
    const int m16 = l & 15;
    const int kq = (l >> 4) * 8;
    const int gr = row0 + w * 16 + m16;

    float4 h[8];
    if (gr < M) {
#pragma unroll
        for (int ks = 0; ks < 4; ++ks) {
            h[ks * 2]     = *(const float4*)&H[gr * 128 + ks * 32 + kq];
            h[ks * 2 + 1] = *(const float4*)&H[gr * 128 + ks * 32 + kq + 4];
        }
    } else {
#pragma unroll
        for (int i = 0; i < 8; ++i) h[i] = make_float4(0.f, 0.f, 0.f, 0.f);
    }

    short8v bfrag[4];
#pragma unroll
    for (int ks = 0; ks < 4; ++ks) {
        uint4v u;
        u[0] = pk2bf(h[ks * 2].x, h[ks * 2].y);
        u[1] = pk2bf(h[ks * 2].z, h[ks * 2].w);
        u[2] = pk2bf(h[ks * 2 + 1].x, h[ks * 2 + 1].y);
        u[3] = pk2bf(h[ks * 2 + 1].z, h[ks * 2 + 1].w);
        bfrag[ks] = __builtin_bit_cast(short8v, u);
    }

    __syncthreads();   // Ws ready

    float4v acc[8];
#pragma unroll
    for (int nt = 0; nt < 8; ++nt) acc[nt] = (float4v){0.f, 0.f, 0.f, 0.f};

#pragma unroll
    for (int ks = 0; ks < 4; ++ks) {
#pragma unroll
        for (int nt = 0; nt < 8; ++nt) {
            short8v afrag = *(const short8v*)&Ws[(nt * 16 + m16) * 136 + ks * 32 + kq];
            acc[nt] = __builtin_amdgcn_mfma_f32_16x16x32_bf16(afrag, bfrag[ks], acc[nt], 0, 0, 0);
        }
    }

    // Per-row absmax across this lane's 32 cols, then across the 4 quarter-
    // lanes sharing row gr (l, l^16, l^32, l^48).
    float mx = 0.f;
#pragma unroll
    for (int nt = 0; nt < 8; ++nt) {
#pragma unroll
        for (int k = 0; k < 4; ++k) mx = fmaxf(mx, fabsf(acc[nt][k]));
    }
    mx = fmaxf(mx, __shfl_xor(mx, 16));
    mx = fmaxf(mx, __shfl_xor(mx, 32));

    const float inv = 127.0f / fmaxf(mx, 1e-20f);

    if (gr < M) {
        const int qd = l >> 4;
        if (qd == 0) S[gr] = mx * (1.0f / 127.0f);
#pragma unroll
        for (int nt = 0; nt < 8; ++nt) {
            unsigned int p = 0;
#pragma unroll
            for (int k = 0; k < 4; ++k) {
                int qi = (int)__builtin_rintf(acc[nt][k] * inv);
                qi = qi > 127 ? 127 : (qi < -127 ? -127 : qi);
                p |= ((unsigned int)(qi + 128) & 0xffu) << (k * 8);   // biased
            }
            *(unsigned int*)&T8[gr * 128 + nt * 16 + qd * 4] = p;
        }
    }
}

// ---------------- Kernel 2: out[n][:] = b + sum_{e} w_e*S[src]*(T8[src][:]-128) ----------------
// One wave per node; lane owns 2 cols (one ushort = 2 biased-uint8 of the row
// -> 128 B/edge gather). Per 64-edge chunk: coalesced vector loads of
// esrc/ew with weight-0 bounds pad (NO serial tail), and the S[src] gather on
// the VECTOR pipe (64 independent, L2-resident) -- fusing what was the
// separate ews kernel. Inner loop: batches of 8 via readlane broadcast
// (pure VALU, no scalar-pipe loads, no dependent chains). Per edge:
// 2 readlane + v_add(B) + 2 v_cvt_f32_ubyte + 2 v_fmac = 7 VALU + 1 VMEM.
// Bias correction -128*B applied once at the end.
__global__ __launch_bounds__(256) void scatter_kernel(const ushort* __restrict__ T16,
                                                      const float* __restrict__ S,
                                                      const int* __restrict__ esrc,
                                                      const float* __restrict__ ew,
                                                      const int* __restrict__ rp,
                                                      const float* __restrict__ b,
                                                      float* __restrict__ out) {
    const int node = blockIdx.x * 4 + (threadIdx.x >> 6);
    const int lane = threadIdx.x & 63;

    const int s = __builtin_amdgcn_readfirstlane(rp[node]);
    const int e = __builtin_amdgcn_readfirstlane(rp[node + 1]);

    float ax = 0.f, ay = 0.f;   // unbiased accumulators
    float B = 0.f;              // sum of ws for bias correction

    for (int c = s; c < e; c += 64) {
        const int idx = c + lane;
        int srcl = 0;
        float wl = 0.f;
        if (idx < e) { srcl = esrc[idx]; wl = ew[idx]; }   // coalesced
        const float wsl = wl * S[srcl];                    // vector-pipe gather
        const int wsbits = __builtin_bit_cast(int, wsl);
        int nn = e - c;
        if (nn > 64) nn = 64;

        for (int j = 0; j < nn; j += 8) {   // uniform trip count; pad ws=0
            int sq[8];
            float wq[8];
            ushort vv[8];
#pragma unroll
            for (int q = 0; q < 8; ++q) {
                sq[q] = __builtin_amdgcn_readlane(srcl, j + q);
                wq[q] = __builtin_bit_cast(float,
                            __builtin_amdgcn_readlane(wsbits, j + q));
            }
#pragma unroll
            for (int q = 0; q < 8; ++q)
                vv[q] = T16[(unsigned int)sq[q] * 64u + (unsigned int)lane];
#pragma unroll
            for (int q = 0; q < 8; ++q) {
                unsigned int v = vv[q];
                B += wq[q];
                ax = fmaf((float)(v & 0xffu), wq[q], ax);          // v_cvt_f32_ubyte0
                ay = fmaf((float)((v >> 8) & 0xffu), wq[q], ay);   // v_cvt_f32_ubyte1
            }
        }
    }

    float2 bias = *(const float2*)&b[lane * 2];
    float ox = fmaf(-128.0f, B, ax) + bias.x;
    float oy = fmaf(-128.0f, B, ay) + bias.y;

    *(float2*)&out[node * 128 + lane * 2] = make_float2(ox, oy);
}

extern "C" void kernel_launch(void* const* d_in, const int* in_sizes, int n_in,
                              void* d_out, int out_size, void* d_ws, size_t ws_size,
                              hipStream_t stream) {
    const float* H    = (const float*)d_in[0];
    const int*   esrc = (const int*)d_in[1];
    const int*   edst = (const int*)d_in[2];
    const float* ew   = (const float*)d_in[3];
    const float* W    = (const float*)d_in[4];
    const float* b    = (const float*)d_in[5];
    float* out = (float*)d_out;

    const int M = in_sizes[0] / IN_DIM;   // 50000 nodes
    const int E = in_sizes[1];            // 1,600,000 edges

    // Workspace layout (~6.8 MB)
    unsigned char* T8 = (unsigned char*)d_ws;                       // M*128 B (biased uint8)
    size_t off = (size_t)M * 128;
    float* S  = (float*)((char*)d_ws + off);                        // M floats
    off += (size_t)M * 4;
    ushort* Wt = (ushort*)((char*)d_ws + off);                      // 128*136*2 B
    off += 128 * 136 * 2;
    int* rp = (int*)((char*)d_ws + off);                            // (M+1) ints

    // Wt transpose (16 blocks)
    prep_kernel<<<16, 256, 0, stream>>>(W, Wt);

    // gemm (biased-uint8 output + per-row scale) + rp tail blocks
    const int nb_gemm = (M + 63) / 64;         // 782
    const int nb_rp   = (M + 1 + 255) / 256;   // 196
    gemm_kernel<<<nb_gemm + nb_rp, 256, 0, stream>>>(H, Wt, T8, S, M, edst, rp, E, nb_gemm);

    scatter_kernel<<<(M + 3) / 4, 256, 0, stream>>>((const ushort*)T8, S, esrc, ew, rp, b, out);
}

// Round 6
// 132.284 us; speedup vs baseline: 1.3499x; 1.0531x over previous
//
#include <hip/hip_runtime.h>

#define IN_DIM 128
#define OUT_DIM 128

typedef __attribute__((ext_vector_type(8))) short short8v;   // 8 bf16 = 4 VGPRs
typedef __attribute__((ext_vector_type(4))) float float4v;
typedef __attribute__((ext_vector_type(4))) unsigned int uint4v;

__device__ __forceinline__ ushort f2bf(float f) {
    unsigned int u = __builtin_bit_cast(unsigned int, f);
    unsigned int r = (u + 0x7fffu + ((u >> 16) & 1u)) >> 16;   // RNE
    return (ushort)r;
}

__device__ __forceinline__ unsigned int pk2bf(float x, float y) {
#if __has_builtin(__builtin_amdgcn_cvt_pk_bf16_f32)
    typedef __attribute__((ext_vector_type(2))) __bf16 bf2;
    bf2 r = __builtin_amdgcn_cvt_pk_bf16_f32(x, y);
    return __builtin_bit_cast(unsigned int, r);
#else
    return (unsigned int)f2bf(x) | ((unsigned int)f2bf(y) << 16);
#endif
}

// ---------------- Kernel 0: prep (Wt only, 16 blocks) ----------------
// Wt[n][k] = bf16(W[k][n]), row stride 136. Coalesced fp32 reads, b32 stores.
__global__ __launch_bounds__(256) void prep_kernel(const float* __restrict__ W,
                                                   ushort* __restrict__ Wt) {
    int k0 = blockIdx.x * 8;
    int n = threadIdx.x & 127;
    int half = threadIdx.x >> 7;
#pragma unroll
    for (int kp = 0; kp < 2; ++kp) {
        int k = k0 + (half * 2 + kp) * 2;
        float v0 = W[k * 128 + n];          // coalesced across lanes
        float v1 = W[(k + 1) * 128 + n];
        *(unsigned int*)&Wt[n * 136 + k] = pk2bf(v0, v1);
    }
}

// ---------------- Kernel 1: T(biased-uint8, per-row scale) = H @ W, + rp tail ----------------
// Blocks [0, nb_gemm): 64-row x 128-col tile, K=128 unrolled (proven core).
// Epilogue: per-row absmax (shfl_xor 16/32 over quarter-lanes), quantize row
// to BIASED uint8 (q+128) with scale S[row] = rowmax/127 -> fetch-cheap
// scatter gather AND single-instruction v_cvt_f32_ubyte decode.
// Blocks [nb_gemm, ...): row_ptr[n] = lower_bound(edst, n) (overlaps gemm).
__global__ __launch_bounds__(256) void gemm_kernel(const float* __restrict__ H,
                                                   const ushort* __restrict__ Wt_g,
                                                   unsigned char* __restrict__ T8,
                                                   float* __restrict__ S, int M,
                                                   const int* __restrict__ edst,
                                                   int* __restrict__ rp,
                                                   int E, int nb_gemm) {
    __shared__ ushort Ws[128 * 136];   // 34816 B

    const int t = threadIdx.x;

    if (blockIdx.x >= nb_gemm) {       // rp tail blocks (block-uniform branch)
        int n = (blockIdx.x - nb_gemm) * 256 + t;
        if (n <= M) {
            int lo = 0, hi = E;
            while (lo < hi) {
                int mid = (lo + hi) >> 1;
                if (edst[mid] < n) lo = mid + 1; else hi = mid;
            }
            rp[n] = lo;
        }
        return;
    }

    const int row0 = blockIdx.x * 64;

#pragma unroll
    for (int f = t; f < 2176; f += 256)
        ((short8v*)Ws)[f] = ((const short8v*)Wt_g)[f];

    const int w = t >> 6;
    const int l = t & 63;
    const int m16 = l & 15;
    const int kq = (l >> 4) * 8;
    const int gr = row0 + w * 16 + m16;

    float4 h[8];
    if (gr < M) {
#pragma unroll
        for (int ks = 0; ks < 4; ++ks) {
            h[ks * 2]     = *(const float4*)&H[gr * 128 + ks * 32 + kq];
            h[ks * 2 + 1] = *(const float4*)&H[gr * 128 + ks * 32 + kq + 4];
        }
    } else {
#pragma unroll
        for (int i = 0; i < 8; ++i) h[i] = make_float4(0.f, 0.f, 0.f, 0.f);
    }

    short8v bfrag[4];
#pragma unroll
    for (int ks = 0; ks < 4; ++ks) {
        uint4v u;
        u[0] = pk2bf(h[ks * 2].x, h[ks * 2].y);
        u[1] = pk2bf(h[ks * 2].z, h[ks * 2].w);
        u[2] = pk2bf(h[ks * 2 + 1].x, h[ks * 2 + 1].y);
        u[3] = pk2bf(h[ks * 2 + 1].z, h[ks * 2 + 1].w);
        bfrag[ks] = __builtin_bit_cast(short8v, u);
    }

    __syncthreads();   // Ws ready

    float4v acc[8];
#pragma unroll
    for (int nt = 0; nt < 8; ++nt) acc[nt] = (float4v){0.f, 0.f, 0.f, 0.f};

#pragma unroll
    for (int ks = 0; ks < 4; ++ks) {
#pragma unroll
        for (int nt = 0; nt < 8; ++nt) {
            short8v afrag = *(const short8v*)&Ws[(nt * 16 + m16) * 136 + ks * 32 + kq];
            acc[nt] = __builtin_amdgcn_mfma_f32_16x16x32_bf16(afrag, bfrag[ks], acc[nt], 0, 0, 0);
        }
    }

    // Per-row absmax across this lane's 32 cols, then across the 4 quarter-
    // lanes sharing row gr (l, l^16, l^32, l^48).
    float mx = 0.f;
#pragma unroll
    for (int nt = 0; nt < 8; ++nt) {
#pragma unroll
        for (int k = 0; k < 4; ++k) mx = fmaxf(mx, fabsf(acc[nt][k]));
    }
    mx = fmaxf(mx, __shfl_xor(mx, 16));
    mx = fmaxf(mx, __shfl_xor(mx, 32));

    const float inv = 127.0f / fmaxf(mx, 1e-20f);

    if (gr < M) {
        const int qd = l >> 4;
        if (qd == 0) S[gr] = mx * (1.0f / 127.0f);
#pragma unroll
        for (int nt = 0; nt < 8; ++nt) {
            unsigned int p = 0;
#pragma unroll
            for (int k = 0; k < 4; ++k) {
                int qi = (int)__builtin_rintf(acc[nt][k] * inv);
                qi = qi > 127 ? 127 : (qi < -127 ? -127 : qi);
                p |= ((unsigned int)(qi + 128) & 0xffu) << (k * 8);   // biased
            }
            *(unsigned int*)&T8[gr * 128 + nt * 16 + qd * 4] = p;
        }
    }
}

// ---------------- Kernel 2: out[n][:] = b + sum_{e} w_e*S[src]*(T8[src][:]-128) ----------------
// One wave per node, EDGE-PAIR structure: lane owns 4 cols (one dword of a
// row). Lanes 0-31 read the EVEN edge's full 128-B row, lanes 32-63 the ODD
// edge's row -> one VMEM instruction retires 2 edges (same lines fetched as
// before: both rows were fully read anyway). Metadata select per pair: 2
// __shfl (ds_bpermute on the idle LDS pipe, 2-address broadcast) + 1 add,
// replacing 2 readlanes PER EDGE on the VALU. Chunk loads keep the weight-0
// pad (no serial tail); S gather stays on the vector pipe. Per edge:
// ~5.5 VALU + 1 DS + 0.5 VMEM (was ~11 VALU+VMEM). Final cross-half combine:
// 5x shfl_xor(32)+add per wave; lanes 0-31 store float4.
__global__ __launch_bounds__(256) void scatter_kernel(const unsigned char* __restrict__ T8,
                                                      const float* __restrict__ S,
                                                      const int* __restrict__ esrc,
                                                      const float* __restrict__ ew,
                                                      const int* __restrict__ rp,
                                                      const float* __restrict__ b,
                                                      float* __restrict__ out) {
    const int node = blockIdx.x * 4 + (threadIdx.x >> 6);
    const int lane = threadIdx.x & 63;
    const int half = lane >> 5;                       // 0: even edges, 1: odd edges
    const unsigned int colb = (lane & 31u) * 4u;      // byte (=col) offset in row

    const int s = __builtin_amdgcn_readfirstlane(rp[node]);
    const int e = __builtin_amdgcn_readfirstlane(rp[node + 1]);

    float ax0 = 0.f, ax1 = 0.f, ax2 = 0.f, ax3 = 0.f;
    float B = 0.f;              // sum of ws over THIS lane's (half's) edges

    for (int c = s; c < e; c += 64) {
        const int idx = c + lane;
        int srcl = 0;
        float wl = 0.f;
        if (idx < e) { srcl = esrc[idx]; wl = ew[idx]; }   // coalesced
        const float wsl = wl * S[srcl];                    // vector-pipe gather
        int nn = e - c;
        if (nn > 64) nn = 64;

        for (int j = 0; j < nn; j += 8) {   // 4 pairs per batch; pad ws=0
            int sqp[4];
            float wsp[4];
            unsigned int vv[4];
#pragma unroll
            for (int p = 0; p < 4; ++p) {
                const int srcLane = j + p * 2 + half;      // my half's edge
                sqp[p] = __shfl(srcl, srcLane);            // ds_bpermute
                wsp[p] = __shfl(wsl, srcLane);             // ds_bpermute
            }
#pragma unroll
            for (int p = 0; p < 4; ++p)
                vv[p] = *(const unsigned int*)(T8 + ((unsigned int)sqp[p] * 128u + colb));
#pragma unroll
            for (int p = 0; p < 4; ++p) {
                const unsigned int v = vv[p];
                const float ws = wsp[p];
                B += ws;
                ax0 = fmaf((float)(v & 0xffu), ws, ax0);           // v_cvt_f32_ubyte0
                ax1 = fmaf((float)((v >> 8) & 0xffu), ws, ax1);    // v_cvt_f32_ubyte1
                ax2 = fmaf((float)((v >> 16) & 0xffu), ws, ax2);   // v_cvt_f32_ubyte2
                ax3 = fmaf((float)(v >> 24), ws, ax3);             // v_cvt_f32_ubyte3
            }
        }
    }

    // Combine even-edge half (lanes 0-31) with odd-edge half (lanes 32-63).
    ax0 += __shfl_xor(ax0, 32);
    ax1 += __shfl_xor(ax1, 32);
    ax2 += __shfl_xor(ax2, 32);
    ax3 += __shfl_xor(ax3, 32);
    B   += __shfl_xor(B, 32);

    if (half == 0) {
        const float4 bb = *(const float4*)&b[colb];
        float4 o;
        o.x = fmaf(-128.0f, B, ax0) + bb.x;
        o.y = fmaf(-128.0f, B, ax1) + bb.y;
        o.z = fmaf(-128.0f, B, ax2) + bb.z;
        o.w = fmaf(-128.0f, B, ax3) + bb.w;
        *(float4*)&out[node * 128 + colb] = o;
    }
}

extern "C" void kernel_launch(void* const* d_in, const int* in_sizes, int n_in,
                              void* d_out, int out_size, void* d_ws, size_t ws_size,
                              hipStream_t stream) {
    const float* H    = (const float*)d_in[0];
    const int*   esrc = (const int*)d_in[1];
    const int*   edst = (const int*)d_in[2];
    const float* ew   = (const float*)d_in[3];
    const float* W    = (const float*)d_in[4];
    const float* b    = (const float*)d_in[5];
    float* out = (float*)d_out;

    const int M = in_sizes[0] / IN_DIM;   // 50000 nodes
    const int E = in_sizes[1];            // 1,600,000 edges

    // Workspace layout (~6.8 MB)
    unsigned char* T8 = (unsigned char*)d_ws;                       // M*128 B (biased uint8)
    size_t off = (size_t)M * 128;
    float* S  = (float*)((char*)d_ws + off);                        // M floats
    off += (size_t)M * 4;
    ushort* Wt = (ushort*)((char*)d_ws + off);                      // 128*136*2 B
    off += 128 * 136 * 2;
    int* rp = (int*)((char*)d_ws + off);                            // (M+1) ints

    // Wt transpose (16 blocks)
    prep_kernel<<<16, 256, 0, stream>>>(W, Wt);

    // gemm (biased-uint8 output + per-row scale) + rp tail blocks
    const int nb_gemm = (M + 63) / 64;         // 782
    const int nb_rp   = (M + 1 + 255) / 256;   // 196
    gemm_kernel<<<nb_gemm + nb_rp, 256, 0, stream>>>(H, Wt, T8, S, M, edst, rp, E, nb_gemm);

    scatter_kernel<<<(M + 3) / 4, 256, 0, stream>>>(T8, S, esrc, ew, rp, b, out);
}